// Round 1
// baseline (265.183 us; speedup 1.0000x reference)
//
#include <hip/hip_runtime.h>
#include <hip/hip_bf16.h>

#define C_DIM 512
#define H_NUM 8
#define D_DIM 64
#define B_NUM 4
#define N_SEQ 2048
#define M_TOT (B_NUM*N_SEQ)   // 8192

typedef unsigned short u16;
typedef unsigned int   u32;
typedef __attribute__((ext_vector_type(8))) short short8;
typedef __attribute__((ext_vector_type(4))) float f32x4;

#define MFMA16 __builtin_amdgcn_mfma_f32_16x16x32_bf16

__device__ __forceinline__ u16 f2b(float f) {
    union { float f; u32 u; } v; v.f = f;
    u32 r = v.u + 0x7FFFu + ((v.u >> 16) & 1u);   // RNE; inputs finite
    return (u16)(r >> 16);
}

// ---------------------------------------------------------------------------
// Kernel 1: QKV projection GEMM (NT): out[m,n] = sum_k X[m,k]*W[n,k] + b[n]
// X fp32 [8192][512] row-major, W fp32 [512][512] row-major (torch Linear W).
// Output bf16. mode 0/1 -> [B][H][N][D]; mode 2 (V) -> [B][H][D][N] (transposed).
// Block: 256 thr = 4 waves (2x2), block tile 64x64, wave tile 32x32, BK=32.
// ---------------------------------------------------------------------------
__global__ __launch_bounds__(256) void k_qkv(const float* __restrict__ X,
                                             const float* __restrict__ W,
                                             const float* __restrict__ bias,
                                             u16* __restrict__ out, int mode)
{
    __shared__ alignas(16) u16 la[4][64][8];   // [k-octet][row][8k] bf16
    __shared__ alignas(16) u16 lb[4][64][8];
    const int t = threadIdx.x;
    const int m0 = blockIdx.x * 64, n0 = blockIdx.y * 64;
    const int w = t >> 6, l = t & 63, lr = l & 15, kq = l >> 4;
    const int wm = w >> 1, wn = w & 1;
    const int srow = t >> 2, skg = t & 3;

    f32x4 acc[2][2] = {};

    for (int k0 = 0; k0 < C_DIM; k0 += 32) {
        const float4* pa = (const float4*)(X + (size_t)(m0 + srow) * C_DIM + k0 + skg * 8);
        float4 a0 = pa[0], a1 = pa[1];
        const float4* pb = (const float4*)(W + (size_t)(n0 + srow) * C_DIM + k0 + skg * 8);
        float4 b0 = pb[0], b1 = pb[1];
        short8 va, vb;
        va[0] = (short)f2b(a0.x); va[1] = (short)f2b(a0.y);
        va[2] = (short)f2b(a0.z); va[3] = (short)f2b(a0.w);
        va[4] = (short)f2b(a1.x); va[5] = (short)f2b(a1.y);
        va[6] = (short)f2b(a1.z); va[7] = (short)f2b(a1.w);
        vb[0] = (short)f2b(b0.x); vb[1] = (short)f2b(b0.y);
        vb[2] = (short)f2b(b0.z); vb[3] = (short)f2b(b0.w);
        vb[4] = (short)f2b(b1.x); vb[5] = (short)f2b(b1.y);
        vb[6] = (short)f2b(b1.z); vb[7] = (short)f2b(b1.w);
        *(short8*)la[skg][srow] = va;
        *(short8*)lb[skg][srow] = vb;
        __syncthreads();

        short8 af0 = *(const short8*)la[kq][wm * 32 + lr];
        short8 af1 = *(const short8*)la[kq][wm * 32 + 16 + lr];
        short8 bf0 = *(const short8*)lb[kq][wn * 32 + lr];
        short8 bf1 = *(const short8*)lb[kq][wn * 32 + 16 + lr];
        acc[0][0] = MFMA16(af0, bf0, acc[0][0], 0, 0, 0);
        acc[0][1] = MFMA16(af0, bf1, acc[0][1], 0, 0, 0);
        acc[1][0] = MFMA16(af1, bf0, acc[1][0], 0, 0, 0);
        acc[1][1] = MFMA16(af1, bf1, acc[1][1], 0, 0, 0);
        __syncthreads();
    }

    #pragma unroll
    for (int fm = 0; fm < 2; ++fm)
    #pragma unroll
    for (int fn = 0; fn < 2; ++fn)
    #pragma unroll
    for (int i = 0; i < 4; ++i) {
        int m = m0 + wm * 32 + fm * 16 + kq * 4 + i;   // C/D: row=(l>>4)*4+reg
        int c = n0 + wn * 32 + fn * 16 + lr;           //      col=l&15
        float v = acc[fm][fn][i] + bias[c];
        int bb = m >> 11, n = m & 2047;
        int h = c >> 6, d = c & 63;
        size_t idx = (mode == 2)
            ? ((size_t)(bb * H_NUM + h) * D_DIM + d) * N_SEQ + n
            : ((size_t)(bb * H_NUM + h) * N_SEQ + n) * D_DIM + d;
        out[idx] = f2b(v);
    }
}

// ---------------------------------------------------------------------------
// Kernel 2: flash attention with position bias.
// Block: one (b,h) x 64 query rows; 4 waves x 16 rows each. KT=64 keys/tile.
// Q,K bf16 [bh][N][D]; Vt bf16 [bh][D][N]. Out bf16 [B][N][C].
// ---------------------------------------------------------------------------
__global__ __launch_bounds__(256) void k_flash(const u16* __restrict__ Q,
                                               const u16* __restrict__ K,
                                               const u16* __restrict__ Vt,
                                               const float* __restrict__ qpos,
                                               u16* __restrict__ attn_out)
{
    __shared__ alignas(16) u16 lds_k[8][64][8];   // [d-octet][key][8] : K[key][d]
    __shared__ alignas(16) u16 lds_v[8][64][8];   // [key-octet][d][8] : V[key][d]
    __shared__ alignas(16) u16 lds_p[4][16][72];  // per-wave P, padded stride 72
    __shared__ float qpx[64], qpy[64], kpx[64], kpy[64];

    const int t = threadIdx.x;
    const int qt = blockIdx.x, bh = blockIdx.y;
    const int b = bh >> 3, h = bh & 7;
    const int w = t >> 6, l = t & 63, lr = l & 15, kg = l >> 4;

    const u16* Qb = Q + (size_t)bh * N_SEQ * D_DIM;
    const u16* Kb = K + (size_t)bh * N_SEQ * D_DIM;
    const u16* Vb = Vt + (size_t)bh * D_DIM * N_SEQ;

    // Q fragments for this wave's 16 rows (A-frag: row=l&15, k-octet=l>>4)
    const int qrow = qt * 64 + w * 16 + lr;
    short8 aq0 = *(const short8*)(Qb + (size_t)qrow * D_DIM + kg * 8);
    short8 aq1 = *(const short8*)(Qb + (size_t)qrow * D_DIM + 32 + kg * 8);

    if (t < 64) {
        qpx[t] = qpos[((size_t)b * N_SEQ + qt * 64 + t) * 4 + 0];
        qpy[t] = qpos[((size_t)b * N_SEQ + qt * 64 + t) * 4 + 1];
    }

    f32x4 acc_o[4] = {};
    float m_run[4], l_run[4];
    #pragma unroll
    for (int i = 0; i < 4; ++i) { m_run[i] = -1e30f; l_run[i] = 0.f; }

    for (int kt = 0; kt < N_SEQ / 64; ++kt) {
        __syncthreads();
        #pragma unroll
        for (int it = 0; it < 2; ++it) {
            int c = t + 256 * it;
            int ckg = c >> 6, cx = c & 63;
            *(short8*)lds_k[ckg][cx] =
                *(const short8*)(Kb + (size_t)(kt * 64 + cx) * D_DIM + ckg * 8);
            *(short8*)lds_v[ckg][cx] =
                *(const short8*)(Vb + (size_t)cx * N_SEQ + kt * 64 + ckg * 8);
        }
        if (t < 64) {
            kpx[t] = qpos[((size_t)b * N_SEQ + kt * 64 + t) * 4 + 0];
            kpy[t] = qpos[((size_t)b * N_SEQ + kt * 64 + t) * 4 + 1];
        }
        __syncthreads();

        // S = Q K^T : 4 col-fragments x (K=64 -> 2 mfma)
        f32x4 s[4] = {};
        #pragma unroll
        for (int fn = 0; fn < 4; ++fn) {
            short8 bk0 = *(const short8*)lds_k[kg][fn * 16 + lr];
            short8 bk1 = *(const short8*)lds_k[4 + kg][fn * 16 + lr];
            s[fn] = MFMA16(aq0, bk0, s[fn], 0, 0, 0);
            s[fn] = MFMA16(aq1, bk1, s[fn], 0, 0, 0);
        }

        // bias + online softmax, per register-row i
        #pragma unroll
        for (int i = 0; i < 4; ++i) {
            int rloc = kg * 4 + i;
            float qx = qpx[w * 16 + rloc], qy = qpy[w * 16 + rloc];
            float sv[4];
            float mx = -1e30f;
            #pragma unroll
            for (int fn = 0; fn < 4; ++fn) {
                float dx = qx - kpx[fn * 16 + lr];
                float dy = qy - kpy[fn * 16 + lr];
                float val = s[fn][i] * 0.125f - 0.1f * sqrtf(dx * dx + dy * dy + 1e-8f);
                sv[fn] = val;
                mx = fmaxf(mx, val);
            }
            mx = fmaxf(mx, __shfl_xor(mx, 1));
            mx = fmaxf(mx, __shfl_xor(mx, 2));
            mx = fmaxf(mx, __shfl_xor(mx, 4));
            mx = fmaxf(mx, __shfl_xor(mx, 8));
            float mnew = fmaxf(m_run[i], mx);
            float corr = __expf(m_run[i] - mnew);
            m_run[i] = mnew;
            float psum = 0.f;
            #pragma unroll
            for (int fn = 0; fn < 4; ++fn) {
                float p = __expf(sv[fn] - mnew);
                sv[fn] = p;
                psum += p;
            }
            psum += __shfl_xor(psum, 1);
            psum += __shfl_xor(psum, 2);
            psum += __shfl_xor(psum, 4);
            psum += __shfl_xor(psum, 8);
            l_run[i] = l_run[i] * corr + psum;
            #pragma unroll
            for (int fd = 0; fd < 4; ++fd) acc_o[fd][i] *= corr;
            #pragma unroll
            for (int fn = 0; fn < 4; ++fn)
                lds_p[w][rloc][fn * 16 + lr] = f2b(sv[fn]);
        }
        __syncthreads();

        // O += P V : A-frag from lds_p rows, B-frag from V^T rows
        short8 ap0 = *(const short8*)&lds_p[w][lr][kg * 8];
        short8 ap1 = *(const short8*)&lds_p[w][lr][32 + kg * 8];
        #pragma unroll
        for (int fd = 0; fd < 4; ++fd) {
            short8 bv0 = *(const short8*)lds_v[kg][fd * 16 + lr];
            short8 bv1 = *(const short8*)lds_v[4 + kg][fd * 16 + lr];
            acc_o[fd] = MFMA16(ap0, bv0, acc_o[fd], 0, 0, 0);
            acc_o[fd] = MFMA16(ap1, bv1, acc_o[fd], 0, 0, 0);
        }
    }

    #pragma unroll
    for (int fd = 0; fd < 4; ++fd)
    #pragma unroll
    for (int i = 0; i < 4; ++i) {
        int m = qt * 64 + w * 16 + kg * 4 + i;
        int c = h * D_DIM + fd * 16 + lr;
        float v = acc_o[fd][i] / l_run[i];
        attn_out[((size_t)b * N_SEQ + m) * C_DIM + c] = f2b(v);
    }
}

// ---------------------------------------------------------------------------
// Kernel 3: output projection GEMM (A bf16) -> fp32 ws
// ---------------------------------------------------------------------------
__global__ __launch_bounds__(256) void k_proj(const u16* __restrict__ A,
                                              const float* __restrict__ W,
                                              const float* __restrict__ bias,
                                              float* __restrict__ out)
{
    __shared__ alignas(16) u16 la[4][64][8];
    __shared__ alignas(16) u16 lb[4][64][8];
    const int t = threadIdx.x;
    const int m0 = blockIdx.x * 64, n0 = blockIdx.y * 64;
    const int w = t >> 6, l = t & 63, lr = l & 15, kq = l >> 4;
    const int wm = w >> 1, wn = w & 1;
    const int srow = t >> 2, skg = t & 3;

    f32x4 acc[2][2] = {};

    for (int k0 = 0; k0 < C_DIM; k0 += 32) {
        *(short8*)la[skg][srow] =
            *(const short8*)(A + (size_t)(m0 + srow) * C_DIM + k0 + skg * 8);
        const float4* pb = (const float4*)(W + (size_t)(n0 + srow) * C_DIM + k0 + skg * 8);
        float4 b0 = pb[0], b1 = pb[1];
        short8 vb;
        vb[0] = (short)f2b(b0.x); vb[1] = (short)f2b(b0.y);
        vb[2] = (short)f2b(b0.z); vb[3] = (short)f2b(b0.w);
        vb[4] = (short)f2b(b1.x); vb[5] = (short)f2b(b1.y);
        vb[6] = (short)f2b(b1.z); vb[7] = (short)f2b(b1.w);
        *(short8*)lb[skg][srow] = vb;
        __syncthreads();

        short8 af0 = *(const short8*)la[kq][wm * 32 + lr];
        short8 af1 = *(const short8*)la[kq][wm * 32 + 16 + lr];
        short8 bf0 = *(const short8*)lb[kq][wn * 32 + lr];
        short8 bf1 = *(const short8*)lb[kq][wn * 32 + 16 + lr];
        acc[0][0] = MFMA16(af0, bf0, acc[0][0], 0, 0, 0);
        acc[0][1] = MFMA16(af0, bf1, acc[0][1], 0, 0, 0);
        acc[1][0] = MFMA16(af1, bf0, acc[1][0], 0, 0, 0);
        acc[1][1] = MFMA16(af1, bf1, acc[1][1], 0, 0, 0);
        __syncthreads();
    }

    #pragma unroll
    for (int fm = 0; fm < 2; ++fm)
    #pragma unroll
    for (int fn = 0; fn < 2; ++fn)
    #pragma unroll
    for (int i = 0; i < 4; ++i) {
        int m = m0 + wm * 32 + fm * 16 + kq * 4 + i;
        int c = n0 + wn * 32 + fn * 16 + lr;
        out[(size_t)m * C_DIM + c] = acc[fm][fn][i] + bias[c];
    }
}

// ---------------------------------------------------------------------------
// Kernel 4: residual + LayerNorm. One block per row, 256 thr, 2 elems/thr.
// ---------------------------------------------------------------------------
__global__ __launch_bounds__(256) void k_ln(const float* __restrict__ proj,
                                            const float* __restrict__ qc,
                                            const float* __restrict__ gamma,
                                            const float* __restrict__ beta,
                                            float* __restrict__ out)
{
    const int r = blockIdx.x;
    const int t = threadIdx.x;
    const size_t base = (size_t)r * C_DIM;
    float h0 = proj[base + t] + qc[base + t];
    float h1 = proj[base + 256 + t] + qc[base + 256 + t];
    float s = h0 + h1, sq = h0 * h0 + h1 * h1;
    #pragma unroll
    for (int m = 1; m < 64; m <<= 1) {
        s += __shfl_xor(s, m);
        sq += __shfl_xor(sq, m);
    }
    __shared__ float ss[4], ssq[4];
    int w = t >> 6;
    if ((t & 63) == 0) { ss[w] = s; ssq[w] = sq; }
    __syncthreads();
    s = ss[0] + ss[1] + ss[2] + ss[3];
    sq = ssq[0] + ssq[1] + ssq[2] + ssq[3];
    float mu = s * (1.f / C_DIM);
    float var = sq * (1.f / C_DIM) - mu * mu;
    float inv = rsqrtf(var + 1e-5f);
    out[base + t]       = (h0 - mu) * inv * gamma[t] + beta[t];
    out[base + 256 + t] = (h1 - mu) * inv * gamma[256 + t] + beta[256 + t];
}

// ---------------------------------------------------------------------------
extern "C" void kernel_launch(void* const* d_in, const int* in_sizes, int n_in,
                              void* d_out, int out_size, void* d_ws, size_t ws_size,
                              hipStream_t stream)
{
    const float* qc    = (const float*)d_in[0];
    const float* qpos  = (const float*)d_in[1];
    const float* Wq    = (const float*)d_in[2];
    const float* bq    = (const float*)d_in[3];
    const float* Wk    = (const float*)d_in[4];
    const float* bk    = (const float*)d_in[5];
    const float* Wv    = (const float*)d_in[6];
    const float* bv    = (const float*)d_in[7];
    const float* Wo    = (const float*)d_in[8];
    const float* bo    = (const float*)d_in[9];
    const float* gamma = (const float*)d_in[10];
    const float* beta  = (const float*)d_in[11];
    float* out = (float*)d_out;

    char* ws = (char*)d_ws;
    const size_t SZ = (size_t)M_TOT * C_DIM;   // elements per [8192][512] buffer
    u16*   q_ws = (u16*)(ws);                  // bf16 [B][H][N][D]
    u16*   k_ws = (u16*)(ws + SZ * 2);         // bf16 [B][H][N][D]
    u16*   v_ws = (u16*)(ws + SZ * 4);         // bf16 [B][H][D][N] (transposed)
    u16*   a_ws = (u16*)(ws + SZ * 6);         // bf16 [B][N][C]
    float* p_ws = (float*)(ws + SZ * 8);       // fp32 [B*N][C]

    dim3 g1(M_TOT / 64, C_DIM / 64);
    k_qkv<<<g1, 256, 0, stream>>>(qc, Wq, bq, q_ws, 0);
    k_qkv<<<g1, 256, 0, stream>>>(qc, Wk, bk, k_ws, 1);
    k_qkv<<<g1, 256, 0, stream>>>(qc, Wv, bv, v_ws, 2);
    k_flash<<<dim3(N_SEQ / 64, B_NUM * H_NUM), 256, 0, stream>>>(q_ws, k_ws, v_ws, qpos, a_ws);
    k_proj<<<g1, 256, 0, stream>>>(a_ws, Wo, bo, p_ws);
    k_ln<<<M_TOT, 256, 0, stream>>>(p_ws, qc, gamma, beta, out);
}

// Round 2
// 211.233 us; speedup vs baseline: 1.2554x; 1.2554x over previous
//
#include <hip/hip_runtime.h>
#include <hip/hip_bf16.h>

#define C_DIM 512
#define H_NUM 8
#define D_DIM 64
#define B_NUM 4
#define N_SEQ 2048
#define M_TOT (B_NUM*N_SEQ)   // 8192

typedef unsigned short u16;
typedef unsigned int   u32;
typedef __attribute__((ext_vector_type(8))) short short8;
typedef __attribute__((ext_vector_type(4))) float f32x4;

#define MFMA16 __builtin_amdgcn_mfma_f32_16x16x32_bf16

__device__ __forceinline__ u16 f2b(float f) {          // RNE
    union { float f; u32 u; } v; v.f = f;
    u32 r = v.u + 0x7FFFu + ((v.u >> 16) & 1u);
    return (u16)(r >> 16);
}
__device__ __forceinline__ u16 f2b_trunc(float f) {    // truncate (P only)
    union { float f; u32 u; } v; v.f = f;
    return (u16)(v.u >> 16);
}
__device__ __forceinline__ float fexp2(float x) {      // raw v_exp_f32 (2^x)
    float r;
    asm("v_exp_f32 %0, %1" : "=v"(r) : "v"(x));
    return r;
}

// ---------------------------------------------------------------------------
// Cast kernels: fp32 -> bf16 (RNE), 8 elems/thread, vectorized.
// ---------------------------------------------------------------------------
__global__ __launch_bounds__(256) void k_cast_x(const float* __restrict__ x,
                                                u16* __restrict__ o)
{
    int i = blockIdx.x * 256 + threadIdx.x;            // i < M_TOT*C_DIM/8
    const float4* p = (const float4*)(x + (size_t)i * 8);
    float4 a = p[0], b = p[1];
    short8 v;
    v[0] = (short)f2b(a.x); v[1] = (short)f2b(a.y);
    v[2] = (short)f2b(a.z); v[3] = (short)f2b(a.w);
    v[4] = (short)f2b(b.x); v[5] = (short)f2b(b.y);
    v[6] = (short)f2b(b.z); v[7] = (short)f2b(b.w);
    *(short8*)(o + (size_t)i * 8) = v;
}

__global__ __launch_bounds__(256) void k_cast_w(const float* __restrict__ w0,
                                                const float* __restrict__ w1,
                                                const float* __restrict__ w2,
                                                const float* __restrict__ w3,
                                                u16* __restrict__ o)
{
    int y = blockIdx.y;
    const float* s = (y == 0) ? w0 : (y == 1) ? w1 : (y == 2) ? w2 : w3;
    int i = blockIdx.x * 256 + threadIdx.x;            // i < 512*512/8
    const float4* p = (const float4*)(s + (size_t)i * 8);
    float4 a = p[0], b = p[1];
    short8 v;
    v[0] = (short)f2b(a.x); v[1] = (short)f2b(a.y);
    v[2] = (short)f2b(a.z); v[3] = (short)f2b(a.w);
    v[4] = (short)f2b(b.x); v[5] = (short)f2b(b.y);
    v[6] = (short)f2b(b.z); v[7] = (short)f2b(b.w);
    *(short8*)(o + (size_t)y * 262144 + (size_t)i * 8) = v;
}

// ---------------------------------------------------------------------------
// Unified NT GEMM: out[m,n] = sum_k A[m,k]*Bw[n,k] + bias[n]
// A bf16 [8192][512], Bw bf16 [512][512]. Tile 128(M)x64(N), BK=32, 4 waves
// along M (wave tile 32x64 = 2x4 frags, 8 mfma : 6 ds_read_b128 per step).
// mode 0/1 -> bf16 [B][H][N][D]; mode 2 -> bf16 [B][H][D][N]; mode 3 -> fp32.
// ---------------------------------------------------------------------------
__global__ __launch_bounds__(256) void k_gemm(const u16* __restrict__ A,
                                              const u16* __restrict__ Bw,
                                              const float* __restrict__ bias,
                                              u16* __restrict__ outb,
                                              float* __restrict__ outf, int mode)
{
    __shared__ alignas(16) u16 la[4][128][8];   // [k-octet][row][8]
    __shared__ alignas(16) u16 lb[4][64][8];
    const int t = threadIdx.x;
    const int m0 = blockIdx.x * 128, n0 = blockIdx.y * 64;
    const int w = t >> 6, l = t & 63, lr = l & 15, kg = l >> 4;
    const int srow = t >> 2, skg = t & 3;

    f32x4 acc[2][4] = {};

    for (int k0 = 0; k0 < C_DIM; k0 += 32) {
        *(short8*)la[skg][srow] =
            *(const short8*)(A + (size_t)(m0 + srow) * C_DIM + k0 + skg * 8);
        *(short8*)la[skg][64 + srow] =
            *(const short8*)(A + (size_t)(m0 + 64 + srow) * C_DIM + k0 + skg * 8);
        *(short8*)lb[skg][srow] =
            *(const short8*)(Bw + (size_t)(n0 + srow) * C_DIM + k0 + skg * 8);
        __syncthreads();

        short8 af0 = *(const short8*)la[kg][w * 32 + lr];
        short8 af1 = *(const short8*)la[kg][w * 32 + 16 + lr];
        short8 bf[4];
        #pragma unroll
        for (int fn = 0; fn < 4; ++fn)
            bf[fn] = *(const short8*)lb[kg][fn * 16 + lr];
        #pragma unroll
        for (int fn = 0; fn < 4; ++fn) {
            acc[0][fn] = MFMA16(af0, bf[fn], acc[0][fn], 0, 0, 0);
            acc[1][fn] = MFMA16(af1, bf[fn], acc[1][fn], 0, 0, 0);
        }
        __syncthreads();
    }

    #pragma unroll
    for (int fm = 0; fm < 2; ++fm)
    #pragma unroll
    for (int fn = 0; fn < 4; ++fn)
    #pragma unroll
    for (int i = 0; i < 4; ++i) {
        int m = m0 + w * 32 + fm * 16 + kg * 4 + i;    // C/D: row=(l>>4)*4+reg
        int c = n0 + fn * 16 + lr;                     //      col=l&15
        float v = acc[fm][fn][i] + bias[c];
        if (mode == 3) {
            outf[(size_t)m * C_DIM + c] = v;
        } else {
            int bb = m >> 11, n = m & 2047;
            int h = c >> 6, d = c & 63;
            size_t idx = (mode == 2)
                ? ((size_t)(bb * H_NUM + h) * D_DIM + d) * N_SEQ + n
                : ((size_t)(bb * H_NUM + h) * N_SEQ + n) * D_DIM + d;
            outb[idx] = f2b(v);
        }
    }
}

// ---------------------------------------------------------------------------
// Flash attention with position bias (log2-domain online softmax).
// Block: one (b,h) x 64 query rows; 4 waves x 16 rows. KT=64 keys/tile.
// ---------------------------------------------------------------------------
__global__ __launch_bounds__(256) void k_flash(const u16* __restrict__ Q,
                                               const u16* __restrict__ K,
                                               const u16* __restrict__ Vt,
                                               const float* __restrict__ qpos,
                                               u16* __restrict__ attn_out)
{
    __shared__ alignas(16) u16 lds_k[8][64][8];   // [d-octet][key][8]
    __shared__ alignas(16) u16 lds_v[8][64][8];   // [key-octet][d][8]
    __shared__ alignas(16) u16 lds_p[4][16][72];  // per-wave P, stride 72
    __shared__ float qpx[64], qpy[64], kpx[64], kpy[64];

    const int t = threadIdx.x;
    const int qt = blockIdx.x, bh = blockIdx.y;
    const int b = bh >> 3, h = bh & 7;
    const int w = t >> 6, l = t & 63, lr = l & 15, kg = l >> 4;

    const float SC = 0.125f * 1.4426950408889634f;   // score scale, log2 units
    const float CB = 0.1f * 1.4426950408889634f;     // bias scale, log2 units

    const u16* Qb = Q + (size_t)bh * N_SEQ * D_DIM;
    const u16* Kb = K + (size_t)bh * N_SEQ * D_DIM;
    const u16* Vb = Vt + (size_t)bh * D_DIM * N_SEQ;

    const int qrow = qt * 64 + w * 16 + lr;
    short8 aq0 = *(const short8*)(Qb + (size_t)qrow * D_DIM + kg * 8);
    short8 aq1 = *(const short8*)(Qb + (size_t)qrow * D_DIM + 32 + kg * 8);

    if (t < 64) {
        qpx[t] = qpos[((size_t)b * N_SEQ + qt * 64 + t) * 4 + 0];
        qpy[t] = qpos[((size_t)b * N_SEQ + qt * 64 + t) * 4 + 1];
    }
    __syncthreads();
    float qx[4], qy[4];
    #pragma unroll
    for (int i = 0; i < 4; ++i) {
        qx[i] = qpx[w * 16 + kg * 4 + i];
        qy[i] = qpy[w * 16 + kg * 4 + i];
    }

    f32x4 acc_o[4] = {};
    float m_run[4], l_run[4];
    #pragma unroll
    for (int i = 0; i < 4; ++i) { m_run[i] = -1e30f; l_run[i] = 0.f; }

    for (int kt = 0; kt < N_SEQ / 64; ++kt) {
        __syncthreads();
        #pragma unroll
        for (int it = 0; it < 2; ++it) {
            int c = t + 256 * it;
            int ckg = c >> 6, cx = c & 63;
            *(short8*)lds_k[ckg][cx] =
                *(const short8*)(Kb + (size_t)(kt * 64 + cx) * D_DIM + ckg * 8);
            *(short8*)lds_v[ckg][cx] =
                *(const short8*)(Vb + (size_t)cx * N_SEQ + kt * 64 + ckg * 8);
        }
        if (t < 64) {
            kpx[t] = qpos[((size_t)b * N_SEQ + kt * 64 + t) * 4 + 0];
            kpy[t] = qpos[((size_t)b * N_SEQ + kt * 64 + t) * 4 + 1];
        }
        __syncthreads();

        // S = Q K^T
        f32x4 s[4] = {};
        #pragma unroll
        for (int fn = 0; fn < 4; ++fn) {
            short8 bk0 = *(const short8*)lds_k[kg][fn * 16 + lr];
            short8 bk1 = *(const short8*)lds_k[4 + kg][fn * 16 + lr];
            s[fn] = MFMA16(aq0, bk0, s[fn], 0, 0, 0);
            s[fn] = MFMA16(aq1, bk1, s[fn], 0, 0, 0);
        }

        float kx[4], ky[4];
        #pragma unroll
        for (int fn = 0; fn < 4; ++fn) {
            kx[fn] = kpx[fn * 16 + lr];
            ky[fn] = kpy[fn * 16 + lr];
        }

        // bias + online softmax (log2 domain), per register-row i
        #pragma unroll
        for (int i = 0; i < 4; ++i) {
            float sv[4];
            float mx;
            #pragma unroll
            for (int fn = 0; fn < 4; ++fn) {
                float dx = qx[i] - kx[fn];
                float dy = qy[i] - ky[fn];
                float d2 = fmaf(dx, dx, fmaf(dy, dy, 1e-8f));
                float dist = d2 * __frsqrt_rn(d2);
                sv[fn] = fmaf(s[fn][i], SC, -CB * dist);
            }
            mx = fmaxf(fmaxf(sv[0], sv[1]), fmaxf(sv[2], sv[3]));
            mx = fmaxf(mx, __shfl_xor(mx, 1));
            mx = fmaxf(mx, __shfl_xor(mx, 2));
            mx = fmaxf(mx, __shfl_xor(mx, 4));
            mx = fmaxf(mx, __shfl_xor(mx, 8));
            float mnew = fmaxf(m_run[i], mx);
            float corr = fexp2(m_run[i] - mnew);
            m_run[i] = mnew;
            float psum = 0.f;
            #pragma unroll
            for (int fn = 0; fn < 4; ++fn) {
                float p = fexp2(sv[fn] - mnew);
                sv[fn] = p;
                psum += p;
            }
            psum += __shfl_xor(psum, 1);
            psum += __shfl_xor(psum, 2);
            psum += __shfl_xor(psum, 4);
            psum += __shfl_xor(psum, 8);
            l_run[i] = fmaf(l_run[i], corr, psum);
            #pragma unroll
            for (int fd = 0; fd < 4; ++fd) acc_o[fd][i] *= corr;
            int rloc = kg * 4 + i;
            #pragma unroll
            for (int fn = 0; fn < 4; ++fn)
                lds_p[w][rloc][fn * 16 + lr] = f2b_trunc(sv[fn]);
        }
        // P is wave-private: order writes before reads without a block barrier
        asm volatile("s_waitcnt lgkmcnt(0)" ::: "memory");

        short8 ap0 = *(const short8*)&lds_p[w][lr][kg * 8];
        short8 ap1 = *(const short8*)&lds_p[w][lr][32 + kg * 8];
        #pragma unroll
        for (int fd = 0; fd < 4; ++fd) {
            short8 bv0 = *(const short8*)lds_v[kg][fd * 16 + lr];
            short8 bv1 = *(const short8*)lds_v[4 + kg][fd * 16 + lr];
            acc_o[fd] = MFMA16(ap0, bv0, acc_o[fd], 0, 0, 0);
            acc_o[fd] = MFMA16(ap1, bv1, acc_o[fd], 0, 0, 0);
        }
    }

    #pragma unroll
    for (int fd = 0; fd < 4; ++fd)
    #pragma unroll
    for (int i = 0; i < 4; ++i) {
        int m = qt * 64 + w * 16 + kg * 4 + i;
        int c = h * D_DIM + fd * 16 + lr;
        float v = acc_o[fd][i] / l_run[i];
        attn_out[((size_t)b * N_SEQ + m) * C_DIM + c] = f2b(v);
    }
}

// ---------------------------------------------------------------------------
// Residual + LayerNorm. One block per row, 256 thr, 2 elems/thr.
// ---------------------------------------------------------------------------
__global__ __launch_bounds__(256) void k_ln(const float* __restrict__ proj,
                                            const float* __restrict__ qc,
                                            const float* __restrict__ gamma,
                                            const float* __restrict__ beta,
                                            float* __restrict__ out)
{
    const int r = blockIdx.x;
    const int t = threadIdx.x;
    const size_t base = (size_t)r * C_DIM;
    float h0 = proj[base + t] + qc[base + t];
    float h1 = proj[base + 256 + t] + qc[base + 256 + t];
    float s = h0 + h1, sq = h0 * h0 + h1 * h1;
    #pragma unroll
    for (int m = 1; m < 64; m <<= 1) {
        s += __shfl_xor(s, m);
        sq += __shfl_xor(sq, m);
    }
    __shared__ float ss[4], ssq[4];
    int w = t >> 6;
    if ((t & 63) == 0) { ss[w] = s; ssq[w] = sq; }
    __syncthreads();
    s = ss[0] + ss[1] + ss[2] + ss[3];
    sq = ssq[0] + ssq[1] + ssq[2] + ssq[3];
    float mu = s * (1.f / C_DIM);
    float var = sq * (1.f / C_DIM) - mu * mu;
    float inv = rsqrtf(var + 1e-5f);
    out[base + t]       = (h0 - mu) * inv * gamma[t] + beta[t];
    out[base + 256 + t] = (h1 - mu) * inv * gamma[256 + t] + beta[256 + t];
}

// ---------------------------------------------------------------------------
extern "C" void kernel_launch(void* const* d_in, const int* in_sizes, int n_in,
                              void* d_out, int out_size, void* d_ws, size_t ws_size,
                              hipStream_t stream)
{
    const float* qc    = (const float*)d_in[0];
    const float* qpos  = (const float*)d_in[1];
    const float* Wq    = (const float*)d_in[2];
    const float* bq    = (const float*)d_in[3];
    const float* Wk    = (const float*)d_in[4];
    const float* bk    = (const float*)d_in[5];
    const float* Wv    = (const float*)d_in[6];
    const float* bv    = (const float*)d_in[7];
    const float* Wo    = (const float*)d_in[8];
    const float* bo    = (const float*)d_in[9];
    const float* gamma = (const float*)d_in[10];
    const float* beta  = (const float*)d_in[11];
    float* out = (float*)d_out;

    char* ws = (char*)d_ws;
    const size_t SZ = (size_t)M_TOT * C_DIM;        // 4194304 elems
    u16*   xb_ws = (u16*)(ws);                      // bf16 X       [8192][512]
    u16*   q_ws  = (u16*)(ws + SZ * 2);             // bf16 Q [B][H][N][D]
    u16*   k_ws  = (u16*)(ws + SZ * 4);             // bf16 K [B][H][N][D]
    u16*   v_ws  = (u16*)(ws + SZ * 6);             // bf16 V [B][H][D][N]
    u16*   a_ws  = (u16*)(ws + SZ * 8);             // bf16 attn out [B][N][C]
    float* p_ws  = (float*)(ws + SZ * 10);          // fp32 proj [8192][512]
    u16*   wb_ws = (u16*)(ws + SZ * 14);            // bf16 Wq|Wk|Wv|Wo (4x256K)

    k_cast_x<<<dim3((int)(SZ / 2048)), 256, 0, stream>>>(qc, xb_ws);
    k_cast_w<<<dim3(128, 4), 256, 0, stream>>>(Wq, Wk, Wv, Wo, wb_ws);

    dim3 gg(M_TOT / 128, C_DIM / 64);
    k_gemm<<<gg, 256, 0, stream>>>(xb_ws, wb_ws,           bq, q_ws, nullptr, 0);
    k_gemm<<<gg, 256, 0, stream>>>(xb_ws, wb_ws + 262144,  bk, k_ws, nullptr, 1);
    k_gemm<<<gg, 256, 0, stream>>>(xb_ws, wb_ws + 524288,  bv, v_ws, nullptr, 2);
    k_flash<<<dim3(N_SEQ / 64, B_NUM * H_NUM), 256, 0, stream>>>(q_ws, k_ws, v_ws, qpos, a_ws);
    k_gemm<<<gg, 256, 0, stream>>>(a_ws, wb_ws + 786432,   bo, nullptr, p_ws, 3);
    k_ln<<<M_TOT, 256, 0, stream>>>(p_ws, qc, gamma, beta, out);
}